// Round 1
// baseline (916.820 us; speedup 1.0000x reference)
//
#include <hip/hip_runtime.h>
#include <math.h>

#define NODES 32768
#define NEDGE 524288
#define ETOT  (NEDGE + NODES)

// ---- order-preserving float<->uint for atomicMax on floats ----
__device__ __forceinline__ unsigned f2ord(float f) {
    unsigned u = __float_as_uint(f);
    return (u & 0x80000000u) ? ~u : (u | 0x80000000u);
}
__device__ __forceinline__ float ord2f(unsigned u) {
    return (u & 0x80000000u) ? __uint_as_float(u & 0x7fffffffu) : __uint_as_float(~u);
}

// ---- init per-layer state: acc[N*64] = bias (or 0), m=0(ordered -inf), denom=0
__global__ void init_layer(unsigned* __restrict__ m, float* __restrict__ denom,
                           float* __restrict__ acc, const float* __restrict__ bias, int H)
{
    int i = blockIdx.x * blockDim.x + threadIdx.x;
    if (i < NODES * 64) acc[i] = bias ? bias[i & 63] : 0.f;
    if (i < NODES * H) { m[i] = 0u; denom[i] = 0.f; }
}

// ---- h = x @ W  (row-major), fused al_s/al_d per-head reductions ----
// blockDim = M (192 or 64), 32 nodes per block. head = wave index (64 cols/head).
template<int K, int M>
__global__ __launch_bounds__(M) void linear_al(
    const float* __restrict__ x, const float* __restrict__ W,
    const float* __restrict__ a_s, const float* __restrict__ a_d,
    float* __restrict__ h, float* __restrict__ als, float* __restrict__ ald)
{
    constexpr int H = M / 64;
    __shared__ float xs[32 * K];
    const int tid = threadIdx.x;
    const int node0 = blockIdx.x * 32;
    for (int i = tid; i < 32 * K; i += M) xs[i] = x[(size_t)node0 * K + i];
    __syncthreads();
    const int head = tid >> 6;
    const int lane = tid & 63;
    const float asv = a_s[tid], adv = a_d[tid];
    for (int i0 = 0; i0 < 32; i0 += 4) {
        float acc[4] = {0.f, 0.f, 0.f, 0.f};
        for (int k = 0; k < K; ++k) {
            const float w = W[k * M + tid];
            #pragma unroll
            for (int r = 0; r < 4; ++r) acc[r] += xs[(i0 + r) * K + k] * w;
        }
        #pragma unroll
        for (int r = 0; r < 4; ++r) {
            const int n = node0 + i0 + r;
            h[(size_t)n * M + tid] = acc[r];
            float ps = acc[r] * asv, pd = acc[r] * adv;
            #pragma unroll
            for (int off = 32; off > 0; off >>= 1) {
                ps += __shfl_down(ps, off, 64);
                pd += __shfl_down(pd, off, 64);
            }
            if (lane == 0) { als[n * H + head] = ps; ald[n * H + head] = pd; }
        }
    }
}

// ---- pass 1 over edges: segment max of leaky_relu(al_s[src]+al_d[dst]) by dst
template<int H>
__global__ void edge_max(const int* __restrict__ srcv, const int* __restrict__ dstv,
                         const float* __restrict__ als, const float* __restrict__ ald,
                         unsigned* __restrict__ m)
{
    int e = blockIdx.x * blockDim.x + threadIdx.x;
    if (e >= ETOT) return;
    int s, d;
    if (e < NEDGE) { s = srcv[e]; d = dstv[e]; } else { s = d = e - NEDGE; }
    #pragma unroll
    for (int hh = 0; hh < H; ++hh) {
        float v = als[s * H + hh] + ald[d * H + hh];
        v = (v >= 0.f) ? v : 0.2f * v;
        atomicMax(&m[d * H + hh], f2ord(v));
    }
}

// ---- pass 2: ex = exp(e - m[dst]); denom[dst] += ex (store ex per edge)
template<int H>
__global__ void edge_exp(const int* __restrict__ srcv, const int* __restrict__ dstv,
                         const float* __restrict__ als, const float* __restrict__ ald,
                         const unsigned* __restrict__ m, float* __restrict__ ex,
                         float* __restrict__ denom)
{
    int e = blockIdx.x * blockDim.x + threadIdx.x;
    if (e >= ETOT) return;
    int s, d;
    if (e < NEDGE) { s = srcv[e]; d = dstv[e]; } else { s = d = e - NEDGE; }
    #pragma unroll
    for (int hh = 0; hh < H; ++hh) {
        float v = als[s * H + hh] + ald[d * H + hh];
        v = (v >= 0.f) ? v : 0.2f * v;
        float mx = ord2f(m[d * H + hh]);
        float exv = expf(v - mx);
        ex[(size_t)e * H + hh] = exv;
        unsafeAtomicAdd(&denom[d * H + hh], exv);
    }
}

// ---- pass 3: acc[dst] += mean_h( alpha * h[src] )  (one wave per edge, lane=channel)
template<int H>
__global__ void edge_scatter(const int* __restrict__ srcv, const int* __restrict__ dstv,
                             const float* __restrict__ h, const float* __restrict__ ex,
                             const float* __restrict__ denom, float* __restrict__ acc)
{
    int e = blockIdx.x * (blockDim.x >> 6) + (threadIdx.x >> 6);
    if (e >= ETOT) return;
    const int lane = threadIdx.x & 63;
    int s, d;
    if (e < NEDGE) { s = srcv[e]; d = dstv[e]; } else { s = d = e - NEDGE; }
    const float* hs = h + (size_t)s * (H * 64);
    float v;
    if (H == 3) {
        float a0 = ex[(size_t)e * 3 + 0] / denom[d * 3 + 0];
        float a1 = ex[(size_t)e * 3 + 1] / denom[d * 3 + 1];
        float a2 = ex[(size_t)e * 3 + 2] / denom[d * 3 + 2];
        v = (a0 * hs[lane] + a1 * hs[64 + lane] + a2 * hs[128 + lane]) * (1.0f / 3.0f);
    } else {
        v = (ex[e] / denom[d]) * hs[lane];
    }
    unsafeAtomicAdd(&acc[(size_t)d * 64 + lane], v);
}

// ---- epilogue for layers 0/1: x_next = gelu_exact(acc + b)
__global__ void gelu_bias(const float* __restrict__ acc, const float* __restrict__ bias,
                          float* __restrict__ xout)
{
    int i = blockIdx.x * blockDim.x + threadIdx.x;
    if (i >= NODES * 64) return;
    float v = acc[i] + bias[i & 63];
    xout[i] = 0.5f * v * (1.f + erff(v * 0.70710678118654752f));
}

extern "C" void kernel_launch(void* const* d_in, const int* in_sizes, int n_in,
                              void* d_out, int out_size, void* d_ws, size_t ws_size,
                              hipStream_t stream) {
    const float* x0  = (const float*)d_in[0];
    const int*   ei  = (const int*)d_in[1];
    const int* srcv = ei;
    const int* dstv = ei + NEDGE;

    const float* W[3]  = { (const float*)d_in[2], (const float*)d_in[6],  (const float*)d_in[10] };
    const float* As[3] = { (const float*)d_in[3], (const float*)d_in[7],  (const float*)d_in[11] };
    const float* Ad[3] = { (const float*)d_in[4], (const float*)d_in[8],  (const float*)d_in[12] };
    const float* B[3]  = { (const float*)d_in[5], (const float*)d_in[9],  (const float*)d_in[13] };

    // workspace layout (floats)
    float* wsf   = (float*)d_ws;
    float* h     = wsf;                              // N*192
    float* als   = h + (size_t)NODES * 192;          // N*3
    float* ald   = als + (size_t)NODES * 3;          // N*3
    unsigned* m  = (unsigned*)(ald + (size_t)NODES * 3); // N*3
    float* denom = (float*)m + (size_t)NODES * 3;    // N*3
    float* ex    = denom + (size_t)NODES * 3;        // ETOT*3
    float* acc   = ex + (size_t)ETOT * 3;            // N*64
    float* x1    = acc + (size_t)NODES * 64;         // N*64
    float* x2    = x1 + (size_t)NODES * 64;          // N*64

    const int TB = 256;
    const int initBlocks = (NODES * 64 + TB - 1) / TB;
    const int edgeBlocks = (ETOT + TB - 1) / TB;
    const int scatBlocks = (ETOT + 3) / 4;           // 4 edges (waves) per 256-thread block
    const int gemmBlocks = NODES / 32;

    // ---------------- layer 0: cin=128, H=3, mean + gelu ----------------
    hipLaunchKernelGGL(init_layer, dim3(initBlocks), dim3(TB), 0, stream, m, denom, acc, (const float*)nullptr, 3);
    hipLaunchKernelGGL((linear_al<128,192>), dim3(gemmBlocks), dim3(192), 0, stream, x0, W[0], As[0], Ad[0], h, als, ald);
    hipLaunchKernelGGL((edge_max<3>), dim3(edgeBlocks), dim3(TB), 0, stream, srcv, dstv, als, ald, m);
    hipLaunchKernelGGL((edge_exp<3>), dim3(edgeBlocks), dim3(TB), 0, stream, srcv, dstv, als, ald, m, ex, denom);
    hipLaunchKernelGGL((edge_scatter<3>), dim3(scatBlocks), dim3(TB), 0, stream, srcv, dstv, h, ex, denom, acc);
    hipLaunchKernelGGL(gelu_bias, dim3(initBlocks), dim3(TB), 0, stream, acc, B[0], x1);

    // ---------------- layer 1: cin=64, H=3, mean + gelu ----------------
    hipLaunchKernelGGL(init_layer, dim3(initBlocks), dim3(TB), 0, stream, m, denom, acc, (const float*)nullptr, 3);
    hipLaunchKernelGGL((linear_al<64,192>), dim3(gemmBlocks), dim3(192), 0, stream, x1, W[1], As[1], Ad[1], h, als, ald);
    hipLaunchKernelGGL((edge_max<3>), dim3(edgeBlocks), dim3(TB), 0, stream, srcv, dstv, als, ald, m);
    hipLaunchKernelGGL((edge_exp<3>), dim3(edgeBlocks), dim3(TB), 0, stream, srcv, dstv, als, ald, m, ex, denom);
    hipLaunchKernelGGL((edge_scatter<3>), dim3(scatBlocks), dim3(TB), 0, stream, srcv, dstv, h, ex, denom, acc);
    hipLaunchKernelGGL(gelu_bias, dim3(initBlocks), dim3(TB), 0, stream, acc, B[1], x2);

    // ---------------- layer 2: cin=64, H=1, concat (direct to out, init=bias) ----------------
    float* outp = (float*)d_out;
    hipLaunchKernelGGL(init_layer, dim3(initBlocks), dim3(TB), 0, stream, m, denom, outp, B[2], 1);
    hipLaunchKernelGGL((linear_al<64,64>), dim3(gemmBlocks), dim3(64), 0, stream, x2, W[2], As[2], Ad[2], h, als, ald);
    hipLaunchKernelGGL((edge_max<1>), dim3(edgeBlocks), dim3(TB), 0, stream, srcv, dstv, als, ald, m);
    hipLaunchKernelGGL((edge_exp<1>), dim3(edgeBlocks), dim3(TB), 0, stream, srcv, dstv, als, ald, m, ex, denom);
    hipLaunchKernelGGL((edge_scatter<1>), dim3(scatBlocks), dim3(TB), 0, stream, srcv, dstv, h, ex, denom, outp);
}

// Round 2
// 399.680 us; speedup vs baseline: 2.2939x; 2.2939x over previous
//
#include <hip/hip_runtime.h>
#include <math.h>

#define NODES 32768
#define NEDGE 524288
#define ETOT  (NEDGE + NODES)

// =================== CSR build (once per call) ===================

__global__ void hist_kernel(const int* __restrict__ dstv, int* __restrict__ cnt)
{
    int e = blockIdx.x * blockDim.x + threadIdx.x;
    if (e >= ETOT) return;
    int d = (e < NEDGE) ? dstv[e] : (e - NEDGE);
    atomicAdd(&cnt[d], 1);
}

// single block, 1024 threads, 32 elements each -> exclusive scan of 32768 counts
__global__ __launch_bounds__(1024) void scan_csr(const int* __restrict__ cnt,
                                                 int* __restrict__ row_ptr,
                                                 int* __restrict__ cursor)
{
    __shared__ int ssum[1024];
    const int t = threadIdx.x;
    const int base = t * 32;
    int local[32];
    int s = 0;
    #pragma unroll
    for (int i = 0; i < 32; ++i) { local[i] = cnt[base + i]; s += local[i]; }
    ssum[t] = s;
    __syncthreads();
    for (int off = 1; off < 1024; off <<= 1) {
        int x = ssum[t];
        int y = (t >= off) ? ssum[t - off] : 0;
        __syncthreads();
        ssum[t] = x + y;
        __syncthreads();
    }
    int run = ssum[t] - s;           // exclusive prefix
    #pragma unroll
    for (int i = 0; i < 32; ++i) {
        row_ptr[base + i] = run;
        cursor[base + i] = run;
        run += local[i];
    }
    if (t == 1023) row_ptr[NODES] = run;
}

__global__ void fill_csr(const int* __restrict__ srcv, const int* __restrict__ dstv,
                         int* __restrict__ cursor, int* __restrict__ col)
{
    int e = blockIdx.x * blockDim.x + threadIdx.x;
    if (e >= ETOT) return;
    int s, d;
    if (e < NEDGE) { s = srcv[e]; d = dstv[e]; } else { s = d = e - NEDGE; }
    int pos = atomicAdd(&cursor[d], 1);
    col[pos] = s;
}

// =================== h = x @ W, fused al_s/al_d reductions ===================
// blockDim = M (192 or 64), 32 nodes per block. head = wave index (64 cols/head).
template<int K, int M>
__global__ __launch_bounds__(M) void linear_al(
    const float* __restrict__ x, const float* __restrict__ W,
    const float* __restrict__ a_s, const float* __restrict__ a_d,
    float* __restrict__ h, float* __restrict__ als, float* __restrict__ ald)
{
    constexpr int H = M / 64;
    __shared__ float xs[32 * K];
    const int tid = threadIdx.x;
    const int node0 = blockIdx.x * 32;
    for (int i = tid; i < 32 * K; i += M) xs[i] = x[(size_t)node0 * K + i];
    __syncthreads();
    const int head = tid >> 6;
    const int lane = tid & 63;
    const float asv = a_s[tid], adv = a_d[tid];
    for (int i0 = 0; i0 < 32; i0 += 4) {
        float acc[4] = {0.f, 0.f, 0.f, 0.f};
        for (int k = 0; k < K; ++k) {
            const float w = W[k * M + tid];
            #pragma unroll
            for (int r = 0; r < 4; ++r) acc[r] += xs[(i0 + r) * K + k] * w;
        }
        #pragma unroll
        for (int r = 0; r < 4; ++r) {
            const int n = node0 + i0 + r;
            h[(size_t)n * M + tid] = acc[r];
            float ps = acc[r] * asv, pd = acc[r] * adv;
            #pragma unroll
            for (int off = 32; off > 0; off >>= 1) {
                ps += __shfl_down(ps, off, 64);
                pd += __shfl_down(pd, off, 64);
            }
            if (lane == 0) { als[n * H + head] = ps; ald[n * H + head] = pd; }
        }
    }
}

// =================== fused per-node softmax + aggregate + bias(+gelu) ===================
// one wave per dst node; lane = output channel. 4 nodes per 256-thread block.
#define EDGE_CAP 256

template<int H, bool GELU>
__global__ __launch_bounds__(256) void node_agg(
    const int* __restrict__ row_ptr, const int* __restrict__ col,
    const float* __restrict__ als, const float* __restrict__ ald,
    const float* __restrict__ htab, const float* __restrict__ bias,
    float* __restrict__ xout)
{
    __shared__ float sex[4][EDGE_CAP * H];
    __shared__ int   scol[4][EDGE_CAP];
    const int wid = threadIdx.x >> 6;
    const int lane = threadIdx.x & 63;
    const int n = blockIdx.x * 4 + wid;
    const int start = row_ptr[n], end = row_ptr[n + 1];
    const int deg = end - start;

    float aldv[H];
    #pragma unroll
    for (int hh = 0; hh < H; ++hh) aldv[hh] = ald[n * H + hh];

    // ---- phase 1: lane-parallel max ----
    float m[H];
    #pragma unroll
    for (int hh = 0; hh < H; ++hh) m[hh] = -INFINITY;
    for (int i = start + lane; i < end; i += 64) {
        int s = col[i];
        #pragma unroll
        for (int hh = 0; hh < H; ++hh) {
            float e = als[s * H + hh] + aldv[hh];
            e = (e >= 0.f) ? e : 0.2f * e;
            m[hh] = fmaxf(m[hh], e);
        }
    }
    #pragma unroll
    for (int hh = 0; hh < H; ++hh)
        #pragma unroll
        for (int off = 1; off < 64; off <<= 1)
            m[hh] = fmaxf(m[hh], __shfl_xor(m[hh], off, 64));

    // ---- phase 2: lane-parallel exp-sum, stash ex + src in LDS ----
    float sum[H];
    #pragma unroll
    for (int hh = 0; hh < H; ++hh) sum[hh] = 0.f;
    for (int i = start + lane; i < end; i += 64) {
        int s = col[i];
        int j = i - start;
        if (j < EDGE_CAP) scol[wid][j] = s;
        #pragma unroll
        for (int hh = 0; hh < H; ++hh) {
            float e = als[s * H + hh] + aldv[hh];
            e = (e >= 0.f) ? e : 0.2f * e;
            float ex = expf(e - m[hh]);
            sum[hh] += ex;
            if (j < EDGE_CAP) sex[wid][j * H + hh] = ex;
        }
    }
    #pragma unroll
    for (int hh = 0; hh < H; ++hh)
        #pragma unroll
        for (int off = 1; off < 64; off <<= 1)
            sum[hh] += __shfl_xor(sum[hh], off, 64);

    const float scale = (H == 1) ? 1.f : (1.f / (float)H);
    float rd[H];
    #pragma unroll
    for (int hh = 0; hh < H; ++hh) rd[hh] = scale / sum[hh];

    // ---- phase 3: wave-wide serial aggregation over in-edges ----
    float acc = 0.f;
    for (int j = 0; j < deg; ++j) {
        int s;
        float w[H];
        if (j < EDGE_CAP) {
            s = scol[wid][j];
            #pragma unroll
            for (int hh = 0; hh < H; ++hh) w[hh] = sex[wid][j * H + hh] * rd[hh];
        } else {                       // fallback (deg > EDGE_CAP): recompute
            s = col[start + j];
            #pragma unroll
            for (int hh = 0; hh < H; ++hh) {
                float e = als[s * H + hh] + aldv[hh];
                e = (e >= 0.f) ? e : 0.2f * e;
                w[hh] = expf(e - m[hh]) * rd[hh];
            }
        }
        const float* hp = htab + (size_t)s * (H * 64);
        #pragma unroll
        for (int hh = 0; hh < H; ++hh) acc = fmaf(w[hh], hp[hh * 64 + lane], acc);
    }

    float v = acc + bias[lane];
    if (GELU) v = 0.5f * v * (1.f + erff(v * 0.70710678118654752f));
    xout[(size_t)n * 64 + lane] = v;
}

// =================== host launch ===================

extern "C" void kernel_launch(void* const* d_in, const int* in_sizes, int n_in,
                              void* d_out, int out_size, void* d_ws, size_t ws_size,
                              hipStream_t stream) {
    const float* x0  = (const float*)d_in[0];
    const int*   ei  = (const int*)d_in[1];
    const int* srcv = ei;
    const int* dstv = ei + NEDGE;

    const float* W[3]  = { (const float*)d_in[2], (const float*)d_in[6],  (const float*)d_in[10] };
    const float* As[3] = { (const float*)d_in[3], (const float*)d_in[7],  (const float*)d_in[11] };
    const float* Ad[3] = { (const float*)d_in[4], (const float*)d_in[8],  (const float*)d_in[12] };
    const float* B[3]  = { (const float*)d_in[5], (const float*)d_in[9],  (const float*)d_in[13] };

    // workspace layout
    float* wsf   = (float*)d_ws;
    float* h     = wsf;                                  // N*192 f32
    float* als   = h + (size_t)NODES * 192;              // N*3
    float* ald   = als + (size_t)NODES * 3;              // N*3
    float* x1    = ald + (size_t)NODES * 3;              // N*64
    float* x2    = x1 + (size_t)NODES * 64;              // N*64
    int* cnt     = (int*)(x2 + (size_t)NODES * 64);      // N
    int* row_ptr = cnt + NODES;                          // N+1
    int* cursor  = row_ptr + NODES + 1;                  // N
    int* col     = cursor + NODES;                       // ETOT

    const int TB = 256;
    const int edgeBlocks = (ETOT + TB - 1) / TB;
    const int nodeBlocks = NODES / 4;
    const int gemmBlocks = NODES / 32;

    // ---- CSR build (self-loops included as virtual edges) ----
    hipMemsetAsync(cnt, 0, NODES * sizeof(int), stream);
    hipLaunchKernelGGL(hist_kernel, dim3(edgeBlocks), dim3(TB), 0, stream, dstv, cnt);
    hipLaunchKernelGGL(scan_csr, dim3(1), dim3(1024), 0, stream, cnt, row_ptr, cursor);
    hipLaunchKernelGGL(fill_csr, dim3(edgeBlocks), dim3(TB), 0, stream, srcv, dstv, cursor, col);

    // ---- layer 0: cin=128, H=3, mean + gelu ----
    hipLaunchKernelGGL((linear_al<128,192>), dim3(gemmBlocks), dim3(192), 0, stream,
                       x0, W[0], As[0], Ad[0], h, als, ald);
    hipLaunchKernelGGL((node_agg<3,true>), dim3(nodeBlocks), dim3(TB), 0, stream,
                       row_ptr, col, als, ald, h, B[0], x1);

    // ---- layer 1: cin=64, H=3, mean + gelu ----
    hipLaunchKernelGGL((linear_al<64,192>), dim3(gemmBlocks), dim3(192), 0, stream,
                       x1, W[1], As[1], Ad[1], h, als, ald);
    hipLaunchKernelGGL((node_agg<3,true>), dim3(nodeBlocks), dim3(TB), 0, stream,
                       row_ptr, col, als, ald, h, B[1], x2);

    // ---- layer 2: cin=64, H=1, concat, no activation ----
    hipLaunchKernelGGL((linear_al<64,64>), dim3(gemmBlocks), dim3(64), 0, stream,
                       x2, W[2], As[2], Ad[2], h, als, ald);
    hipLaunchKernelGGL((node_agg<1,false>), dim3(nodeBlocks), dim3(TB), 0, stream,
                       row_ptr, col, als, ald, h, B[2], (float*)d_out);
}

// Round 3
// 356.278 us; speedup vs baseline: 2.5733x; 1.1218x over previous
//
#include <hip/hip_runtime.h>
#include <math.h>

#define NODES 32768
#define NEDGE 524288
#define ETOT  (NEDGE + NODES)

// =================== CSR build (once per call) ===================

__global__ void hist_kernel(const int* __restrict__ dstv, int* __restrict__ cnt)
{
    int e = blockIdx.x * blockDim.x + threadIdx.x;
    if (e >= ETOT) return;
    int d = (e < NEDGE) ? dstv[e] : (e - NEDGE);
    atomicAdd(&cnt[d], 1);
}

// single block, 1024 threads, 32 elements each -> exclusive scan of 32768 counts
__global__ __launch_bounds__(1024) void scan_csr(const int* __restrict__ cnt,
                                                 int* __restrict__ row_ptr,
                                                 int* __restrict__ cursor)
{
    __shared__ int ssum[1024];
    const int t = threadIdx.x;
    const int base = t * 32;
    int local[32];
    int s = 0;
    #pragma unroll
    for (int i = 0; i < 32; ++i) { local[i] = cnt[base + i]; s += local[i]; }
    ssum[t] = s;
    __syncthreads();
    for (int off = 1; off < 1024; off <<= 1) {
        int x = ssum[t];
        int y = (t >= off) ? ssum[t - off] : 0;
        __syncthreads();
        ssum[t] = x + y;
        __syncthreads();
    }
    int run = ssum[t] - s;           // exclusive prefix
    #pragma unroll
    for (int i = 0; i < 32; ++i) {
        row_ptr[base + i] = run;
        cursor[base + i] = run;
        run += local[i];
    }
    if (t == 1023) row_ptr[NODES] = run;
}

__global__ void fill_csr(const int* __restrict__ srcv, const int* __restrict__ dstv,
                         int* __restrict__ cursor, int* __restrict__ col)
{
    int e = blockIdx.x * blockDim.x + threadIdx.x;
    if (e >= ETOT) return;
    int s, d;
    if (e < NEDGE) { s = srcv[e]; d = dstv[e]; } else { s = d = e - NEDGE; }
    int pos = atomicAdd(&cursor[d], 1);
    col[pos] = s;
}

// =================== W transpose: WT[c][k] = W[k][c] ===================
__global__ void transpose_w(const float* __restrict__ W, float* __restrict__ WT,
                            int K, int M)
{
    int i = blockIdx.x * blockDim.x + threadIdx.x;   // i = c*K + k (coalesced write)
    if (i >= M * K) return;
    int c = i / K, k = i - c * K;
    WT[i] = W[k * M + c];
}

// =================== h = x @ W, fused al_s/al_d reductions ===================
// grid: (NODES/128, H). block: 256 threads.
// thread (cg = tid&15, ng = tid>>4) owns 8 nodes (ng*8..+7) x 4 cols (cg*4..+3)
// of this head's 64-col slab. W^T rows read from global (L1-resident);
// x tile staged in LDS.
template<int K, int KTILE>
__global__ __launch_bounds__(256) void linear_al(
    const float* __restrict__ x, const float* __restrict__ wt,   // wt: [M][K]
    const float* __restrict__ a_s, const float* __restrict__ a_d,
    float* __restrict__ h, float* __restrict__ als, float* __restrict__ ald,
    int H)
{
    __shared__ float xs[128][KTILE];
    const int tid = threadIdx.x;
    const int cg = tid & 15;
    const int ng = tid >> 4;
    const int head = blockIdx.y;
    const int n0 = blockIdx.x * 128;
    const int M = H << 6;
    const int c0 = head * 64 + cg * 4;

    const float* w0 = wt + (size_t)(c0 + 0) * K;
    const float* w1 = wt + (size_t)(c0 + 1) * K;
    const float* w2 = wt + (size_t)(c0 + 2) * K;
    const float* w3 = wt + (size_t)(c0 + 3) * K;

    float acc[8][4];
    #pragma unroll
    for (int r = 0; r < 8; ++r)
        #pragma unroll
        for (int j = 0; j < 4; ++j) acc[r][j] = 0.f;

    for (int k0 = 0; k0 < K; k0 += KTILE) {
        // ---- stage x tile: 128 rows x KTILE floats ----
        #pragma unroll
        for (int it = 0; it < KTILE / 8; ++it) {
            int u = tid + it * 256;                 // over 128*(KTILE/4) float4s
            int row = u >> 4;                        // KTILE/4 == 16
            int kq = u & 15;
            float4 v = *reinterpret_cast<const float4*>(
                &x[(size_t)(n0 + row) * K + k0 + kq * 4]);
            *reinterpret_cast<float4*>(&xs[row][kq * 4]) = v;
        }
        __syncthreads();

        #pragma unroll 4
        for (int kk = 0; kk < KTILE; kk += 4) {
            float4 wv0 = *reinterpret_cast<const float4*>(&w0[k0 + kk]);
            float4 wv1 = *reinterpret_cast<const float4*>(&w1[k0 + kk]);
            float4 wv2 = *reinterpret_cast<const float4*>(&w2[k0 + kk]);
            float4 wv3 = *reinterpret_cast<const float4*>(&w3[k0 + kk]);
            #pragma unroll
            for (int r = 0; r < 8; ++r) {
                float4 xv = *reinterpret_cast<const float4*>(&xs[ng * 8 + r][kk]);
                acc[r][0] = fmaf(xv.x, wv0.x, fmaf(xv.y, wv0.y, fmaf(xv.z, wv0.z, fmaf(xv.w, wv0.w, acc[r][0]))));
                acc[r][1] = fmaf(xv.x, wv1.x, fmaf(xv.y, wv1.y, fmaf(xv.z, wv1.z, fmaf(xv.w, wv1.w, acc[r][1]))));
                acc[r][2] = fmaf(xv.x, wv2.x, fmaf(xv.y, wv2.y, fmaf(xv.z, wv2.z, fmaf(xv.w, wv2.w, acc[r][2]))));
                acc[r][3] = fmaf(xv.x, wv3.x, fmaf(xv.y, wv3.y, fmaf(xv.z, wv3.z, fmaf(xv.w, wv3.w, acc[r][3]))));
            }
        }
        __syncthreads();
    }

    // ---- epilogue: write h, reduce al_s/al_d across the 16 col-groups ----
    const float* asp = a_s + head * 64 + cg * 4;
    const float* adp = a_d + head * 64 + cg * 4;
    const float s0 = asp[0], s1 = asp[1], s2 = asp[2], s3 = asp[3];
    const float d0 = adp[0], d1 = adp[1], d2 = adp[2], d3 = adp[3];

    #pragma unroll
    for (int r = 0; r < 8; ++r) {
        const int n = n0 + ng * 8 + r;
        float4 hv;
        hv.x = acc[r][0]; hv.y = acc[r][1]; hv.z = acc[r][2]; hv.w = acc[r][3];
        *reinterpret_cast<float4*>(&h[(size_t)n * M + c0]) = hv;
        float ps = acc[r][0] * s0 + acc[r][1] * s1 + acc[r][2] * s2 + acc[r][3] * s3;
        float pd = acc[r][0] * d0 + acc[r][1] * d1 + acc[r][2] * d2 + acc[r][3] * d3;
        #pragma unroll
        for (int off = 1; off < 16; off <<= 1) {
            ps += __shfl_xor(ps, off, 64);
            pd += __shfl_xor(pd, off, 64);
        }
        if (cg == 0) { als[n * H + head] = ps; ald[n * H + head] = pd; }
    }
}

// =================== fused per-node softmax + aggregate + bias(+gelu) ===================
// one wave per dst node; lane = output channel. 4 nodes per 256-thread block.
#define EDGE_CAP 256

template<int H, bool GELU>
__global__ __launch_bounds__(256) void node_agg(
    const int* __restrict__ row_ptr, const int* __restrict__ col,
    const float* __restrict__ als, const float* __restrict__ ald,
    const float* __restrict__ htab, const float* __restrict__ bias,
    float* __restrict__ xout)
{
    __shared__ float sex[4][EDGE_CAP * H];
    __shared__ int   scol[4][EDGE_CAP];
    const int wid = threadIdx.x >> 6;
    const int lane = threadIdx.x & 63;
    const int n = blockIdx.x * 4 + wid;
    const int start = row_ptr[n], end = row_ptr[n + 1];
    const int deg = end - start;

    float aldv[H];
    #pragma unroll
    for (int hh = 0; hh < H; ++hh) aldv[hh] = ald[n * H + hh];

    // ---- phase 1: lane-parallel max ----
    float m[H];
    #pragma unroll
    for (int hh = 0; hh < H; ++hh) m[hh] = -INFINITY;
    for (int i = start + lane; i < end; i += 64) {
        int s = col[i];
        #pragma unroll
        for (int hh = 0; hh < H; ++hh) {
            float e = als[s * H + hh] + aldv[hh];
            e = (e >= 0.f) ? e : 0.2f * e;
            m[hh] = fmaxf(m[hh], e);
        }
    }
    #pragma unroll
    for (int hh = 0; hh < H; ++hh)
        #pragma unroll
        for (int off = 1; off < 64; off <<= 1)
            m[hh] = fmaxf(m[hh], __shfl_xor(m[hh], off, 64));

    // ---- phase 2: lane-parallel exp-sum, stash ex + src in LDS ----
    float sum[H];
    #pragma unroll
    for (int hh = 0; hh < H; ++hh) sum[hh] = 0.f;
    for (int i = start + lane; i < end; i += 64) {
        int s = col[i];
        int j = i - start;
        if (j < EDGE_CAP) scol[wid][j] = s;
        #pragma unroll
        for (int hh = 0; hh < H; ++hh) {
            float e = als[s * H + hh] + aldv[hh];
            e = (e >= 0.f) ? e : 0.2f * e;
            float ex = expf(e - m[hh]);
            sum[hh] += ex;
            if (j < EDGE_CAP) sex[wid][j * H + hh] = ex;
        }
    }
    #pragma unroll
    for (int hh = 0; hh < H; ++hh)
        #pragma unroll
        for (int off = 1; off < 64; off <<= 1)
            sum[hh] += __shfl_xor(sum[hh], off, 64);

    const float scale = (H == 1) ? 1.f : (1.f / (float)H);
    float rd[H];
    #pragma unroll
    for (int hh = 0; hh < H; ++hh) rd[hh] = scale / sum[hh];

    // ---- phase 3: wave-wide serial aggregation over in-edges ----
    float acc = 0.f;
    for (int j = 0; j < deg; ++j) {
        int s;
        float w[H];
        if (j < EDGE_CAP) {
            s = scol[wid][j];
            #pragma unroll
            for (int hh = 0; hh < H; ++hh) w[hh] = sex[wid][j * H + hh] * rd[hh];
        } else {                       // fallback (deg > EDGE_CAP): recompute
            s = col[start + j];
            #pragma unroll
            for (int hh = 0; hh < H; ++hh) {
                float e = als[s * H + hh] + aldv[hh];
                e = (e >= 0.f) ? e : 0.2f * e;
                w[hh] = expf(e - m[hh]) * rd[hh];
            }
        }
        const float* hp = htab + (size_t)s * (H * 64);
        #pragma unroll
        for (int hh = 0; hh < H; ++hh) acc = fmaf(w[hh], hp[hh * 64 + lane], acc);
    }

    float v = acc + bias[lane];
    if (GELU) v = 0.5f * v * (1.f + erff(v * 0.70710678118654752f));
    xout[(size_t)n * 64 + lane] = v;
}

// =================== host launch ===================

extern "C" void kernel_launch(void* const* d_in, const int* in_sizes, int n_in,
                              void* d_out, int out_size, void* d_ws, size_t ws_size,
                              hipStream_t stream) {
    const float* x0  = (const float*)d_in[0];
    const int*   ei  = (const int*)d_in[1];
    const int* srcv = ei;
    const int* dstv = ei + NEDGE;

    const float* W[3]  = { (const float*)d_in[2], (const float*)d_in[6],  (const float*)d_in[10] };
    const float* As[3] = { (const float*)d_in[3], (const float*)d_in[7],  (const float*)d_in[11] };
    const float* Ad[3] = { (const float*)d_in[4], (const float*)d_in[8],  (const float*)d_in[12] };
    const float* B[3]  = { (const float*)d_in[5], (const float*)d_in[9],  (const float*)d_in[13] };

    // workspace layout
    float* wsf   = (float*)d_ws;
    float* h     = wsf;                                  // N*192 f32
    float* als   = h + (size_t)NODES * 192;              // N*3
    float* ald   = als + (size_t)NODES * 3;              // N*3
    float* x1    = ald + (size_t)NODES * 3;              // N*64
    float* x2    = x1 + (size_t)NODES * 64;              // N*64
    float* wt0   = x2 + (size_t)NODES * 64;              // 192*128
    float* wt1   = wt0 + 192 * 128;                      // 192*64
    float* wt2   = wt1 + 192 * 64;                       // 64*64
    int* cnt     = (int*)(wt2 + 64 * 64);                // N
    int* row_ptr = cnt + NODES;                          // N+1
    int* cursor  = row_ptr + NODES + 1;                  // N
    int* col     = cursor + NODES;                       // ETOT

    const int TB = 256;
    const int edgeBlocks = (ETOT + TB - 1) / TB;
    const int nodeBlocks = NODES / 4;

    // ---- CSR build (self-loops included as virtual edges) ----
    hipMemsetAsync(cnt, 0, NODES * sizeof(int), stream);
    hipLaunchKernelGGL(hist_kernel, dim3(edgeBlocks), dim3(TB), 0, stream, dstv, cnt);
    hipLaunchKernelGGL(scan_csr, dim3(1), dim3(1024), 0, stream, cnt, row_ptr, cursor);
    hipLaunchKernelGGL(fill_csr, dim3(edgeBlocks), dim3(TB), 0, stream, srcv, dstv, cursor, col);

    // ---- W transposes ----
    hipLaunchKernelGGL(transpose_w, dim3((192 * 128 + 255) / 256), dim3(TB), 0, stream, W[0], wt0, 128, 192);
    hipLaunchKernelGGL(transpose_w, dim3((192 * 64 + 255) / 256), dim3(TB), 0, stream, W[1], wt1, 64, 192);
    hipLaunchKernelGGL(transpose_w, dim3((64 * 64 + 255) / 256), dim3(TB), 0, stream, W[2], wt2, 64, 64);

    // ---- layer 0: cin=128, H=3, mean + gelu ----
    hipLaunchKernelGGL((linear_al<128, 64>), dim3(NODES / 128, 3), dim3(TB), 0, stream,
                       x0, wt0, As[0], Ad[0], h, als, ald, 3);
    hipLaunchKernelGGL((node_agg<3, true>), dim3(nodeBlocks), dim3(TB), 0, stream,
                       row_ptr, col, als, ald, h, B[0], x1);

    // ---- layer 1: cin=64, H=3, mean + gelu ----
    hipLaunchKernelGGL((linear_al<64, 64>), dim3(NODES / 128, 3), dim3(TB), 0, stream,
                       x1, wt1, As[1], Ad[1], h, als, ald, 3);
    hipLaunchKernelGGL((node_agg<3, true>), dim3(nodeBlocks), dim3(TB), 0, stream,
                       row_ptr, col, als, ald, h, B[1], x2);

    // ---- layer 2: cin=64, H=1, concat, no activation ----
    hipLaunchKernelGGL((linear_al<64, 64>), dim3(NODES / 128, 1), dim3(TB), 0, stream,
                       x2, wt2, As[2], Ad[2], h, als, ald, 1);
    hipLaunchKernelGGL((node_agg<1, false>), dim3(nodeBlocks), dim3(TB), 0, stream,
                       row_ptr, col, als, ald, h, B[2], (float*)d_out);
}

// Round 4
// 290.556 us; speedup vs baseline: 3.1554x; 1.2262x over previous
//
#include <hip/hip_runtime.h>
#include <math.h>

#define NODES 32768
#define NEDGE 524288
#define ETOT  (NEDGE + NODES)

// =================== CSR build (once per call) ===================

__global__ void hist_kernel(const int* __restrict__ dstv, int* __restrict__ cnt)
{
    int e = blockIdx.x * blockDim.x + threadIdx.x;
    if (e >= ETOT) return;
    int d = (e < NEDGE) ? dstv[e] : (e - NEDGE);
    atomicAdd(&cnt[d], 1);
}

// single block, 1024 threads, 32 elements each -> exclusive scan of 32768 counts
__global__ __launch_bounds__(1024) void scan_csr(const int* __restrict__ cnt,
                                                 int* __restrict__ row_ptr,
                                                 int* __restrict__ cursor)
{
    __shared__ int ssum[1024];
    const int t = threadIdx.x;
    const int base = t * 32;
    int local[32];
    int s = 0;
    #pragma unroll
    for (int i = 0; i < 32; ++i) { local[i] = cnt[base + i]; s += local[i]; }
    ssum[t] = s;
    __syncthreads();
    for (int off = 1; off < 1024; off <<= 1) {
        int x = ssum[t];
        int y = (t >= off) ? ssum[t - off] : 0;
        __syncthreads();
        ssum[t] = x + y;
        __syncthreads();
    }
    int run = ssum[t] - s;           // exclusive prefix
    #pragma unroll
    for (int i = 0; i < 32; ++i) {
        row_ptr[base + i] = run;
        cursor[base + i] = run;
        run += local[i];
    }
    if (t == 1023) row_ptr[NODES] = run;
}

__global__ void fill_csr(const int* __restrict__ srcv, const int* __restrict__ dstv,
                         int* __restrict__ cursor, int* __restrict__ col)
{
    int e = blockIdx.x * blockDim.x + threadIdx.x;
    if (e >= ETOT) return;
    int s, d;
    if (e < NEDGE) { s = srcv[e]; d = dstv[e]; } else { s = d = e - NEDGE; }
    int pos = atomicAdd(&cursor[d], 1);
    col[pos] = s;
}

// =================== h = x @ W, fused al_s/al_d reductions ===================
// grid: (NODES/128, H). block: 256 threads.
// thread (cg = tid&15, ng = tid>>4) owns 8 nodes (ng*8..+7) x 4 cols (cg*4..+3)
// of this head's 64-col slab.
// x tile: LDS, node-major float4 slots with XOR swizzle (conflict-free reads).
// W tile: LDS, k-major [kk][c] (natural float4 of 4 cols; 2-way = free).
template<int K>
__global__ __launch_bounds__(256) void linear_al(
    const float* __restrict__ x, const float* __restrict__ W,   // W: [K][M] k-major
    const float* __restrict__ a_s, const float* __restrict__ a_d,
    float* __restrict__ h, float* __restrict__ als, float* __restrict__ ald,
    int H)
{
    constexpr int KT = 64;
    __shared__ float xs[128 * KT];   // slot layout: row*16 + (q ^ ((row>>3)&3)), q = k/4
    __shared__ float ws[KT * 64];    // [kk][c]
    const int tid = threadIdx.x;
    const int cg = tid & 15;
    const int ng = tid >> 4;
    const int head = blockIdx.y;
    const int n0 = blockIdx.x * 128;
    const int M = H << 6;

    float acc[8][4];
    #pragma unroll
    for (int r = 0; r < 8; ++r)
        #pragma unroll
        for (int j = 0; j < 4; ++j) acc[r][j] = 0.f;

    for (int k0 = 0; k0 < K; k0 += KT) {
        // ---- stage x tile: 128 rows x 16 float4 slots, swizzled ----
        #pragma unroll
        for (int it = 0; it < 8; ++it) {
            int u = tid + it * 256;
            int row = u >> 4, q = u & 15;
            float4 v = *reinterpret_cast<const float4*>(
                &x[(size_t)(n0 + row) * K + k0 + q * 4]);
            int slot = row * 16 + (q ^ ((row >> 3) & 3));
            *reinterpret_cast<float4*>(&xs[slot * 4]) = v;
        }
        // ---- stage W tile: 64 kk x 16 float4 col-slots (this head's slab) ----
        #pragma unroll
        for (int it = 0; it < 4; ++it) {
            int u = tid + it * 256;
            int kk = u >> 4, cq = u & 15;
            float4 v = *reinterpret_cast<const float4*>(
                &W[(size_t)(k0 + kk) * M + head * 64 + cq * 4]);
            *reinterpret_cast<float4*>(&ws[kk * 64 + cq * 4]) = v;
        }
        __syncthreads();

        #pragma unroll
        for (int q = 0; q < 16; ++q) {
            float4 wv[4];
            #pragma unroll
            for (int i = 0; i < 4; ++i)
                wv[i] = *reinterpret_cast<const float4*>(&ws[(q * 4 + i) * 64 + cg * 4]);
            #pragma unroll
            for (int r = 0; r < 8; ++r) {
                const int row = ng * 8 + r;
                const int slot = row * 16 + (q ^ ((row >> 3) & 3));
                float4 xv = *reinterpret_cast<const float4*>(&xs[slot * 4]);
                acc[r][0] = fmaf(xv.x, wv[0].x, fmaf(xv.y, wv[1].x, fmaf(xv.z, wv[2].x, fmaf(xv.w, wv[3].x, acc[r][0]))));
                acc[r][1] = fmaf(xv.x, wv[0].y, fmaf(xv.y, wv[1].y, fmaf(xv.z, wv[2].y, fmaf(xv.w, wv[3].y, acc[r][1]))));
                acc[r][2] = fmaf(xv.x, wv[0].z, fmaf(xv.y, wv[1].z, fmaf(xv.z, wv[2].z, fmaf(xv.w, wv[3].z, acc[r][2]))));
                acc[r][3] = fmaf(xv.x, wv[0].w, fmaf(xv.y, wv[1].w, fmaf(xv.z, wv[2].w, fmaf(xv.w, wv[3].w, acc[r][3]))));
            }
        }
        __syncthreads();
    }

    // ---- epilogue: write h, reduce al_s/al_d across the 16 col-groups ----
    const int c0 = head * 64 + cg * 4;
    const float* asp = a_s + c0;
    const float* adp = a_d + c0;
    const float s0 = asp[0], s1 = asp[1], s2 = asp[2], s3 = asp[3];
    const float d0 = adp[0], d1 = adp[1], d2 = adp[2], d3 = adp[3];

    #pragma unroll
    for (int r = 0; r < 8; ++r) {
        const int n = n0 + ng * 8 + r;
        float4 hv;
        hv.x = acc[r][0]; hv.y = acc[r][1]; hv.z = acc[r][2]; hv.w = acc[r][3];
        *reinterpret_cast<float4*>(&h[(size_t)n * M + c0]) = hv;
        float ps = acc[r][0] * s0 + acc[r][1] * s1 + acc[r][2] * s2 + acc[r][3] * s3;
        float pd = acc[r][0] * d0 + acc[r][1] * d1 + acc[r][2] * d2 + acc[r][3] * d3;
        #pragma unroll
        for (int off = 1; off < 16; off <<= 1) {
            ps += __shfl_xor(ps, off, 64);
            pd += __shfl_xor(pd, off, 64);
        }
        if (cg == 0) { als[n * H + head] = ps; ald[n * H + head] = pd; }
    }
}

// =================== fused per-node softmax + aggregate + bias(+gelu) ===================
// one wave per dst node; lane = output channel. 4 nodes per 256-thread block.
#define EDGE_CAP 256

template<int H, bool GELU>
__global__ __launch_bounds__(256) void node_agg(
    const int* __restrict__ row_ptr, const int* __restrict__ col,
    const float* __restrict__ als, const float* __restrict__ ald,
    const float* __restrict__ htab, const float* __restrict__ bias,
    float* __restrict__ xout)
{
    __shared__ float sex[4][EDGE_CAP * H];
    __shared__ int   scol[4][EDGE_CAP];
    const int wid = threadIdx.x >> 6;
    const int lane = threadIdx.x & 63;
    const int n = blockIdx.x * 4 + wid;
    const int start = row_ptr[n], end = row_ptr[n + 1];
    const int deg = end - start;

    float aldv[H];
    #pragma unroll
    for (int hh = 0; hh < H; ++hh) aldv[hh] = ald[n * H + hh];

    // ---- phase 1: lane-parallel max ----
    float m[H];
    #pragma unroll
    for (int hh = 0; hh < H; ++hh) m[hh] = -INFINITY;
    for (int i = start + lane; i < end; i += 64) {
        int s = col[i];
        #pragma unroll
        for (int hh = 0; hh < H; ++hh) {
            float e = als[s * H + hh] + aldv[hh];
            e = (e >= 0.f) ? e : 0.2f * e;
            m[hh] = fmaxf(m[hh], e);
        }
    }
    #pragma unroll
    for (int hh = 0; hh < H; ++hh)
        #pragma unroll
        for (int off = 1; off < 64; off <<= 1)
            m[hh] = fmaxf(m[hh], __shfl_xor(m[hh], off, 64));

    // ---- phase 2: lane-parallel exp-sum, stash ex + src in LDS ----
    float sum[H];
    #pragma unroll
    for (int hh = 0; hh < H; ++hh) sum[hh] = 0.f;
    for (int i = start + lane; i < end; i += 64) {
        int s = col[i];
        int j = i - start;
        if (j < EDGE_CAP) scol[wid][j] = s;
        #pragma unroll
        for (int hh = 0; hh < H; ++hh) {
            float e = als[s * H + hh] + aldv[hh];
            e = (e >= 0.f) ? e : 0.2f * e;
            float ex = expf(e - m[hh]);
            sum[hh] += ex;
            if (j < EDGE_CAP) sex[wid][j * H + hh] = ex;
        }
    }
    #pragma unroll
    for (int hh = 0; hh < H; ++hh)
        #pragma unroll
        for (int off = 1; off < 64; off <<= 1)
            sum[hh] += __shfl_xor(sum[hh], off, 64);

    const float scale = (H == 1) ? 1.f : (1.f / (float)H);
    float rd[H];
    #pragma unroll
    for (int hh = 0; hh < H; ++hh) rd[hh] = scale / sum[hh];

    // ---- phase 3: wave-wide serial aggregation over in-edges ----
    float acc = 0.f;
    for (int j = 0; j < deg; ++j) {
        int s;
        float w[H];
        if (j < EDGE_CAP) {
            s = scol[wid][j];
            #pragma unroll
            for (int hh = 0; hh < H; ++hh) w[hh] = sex[wid][j * H + hh] * rd[hh];
        } else {                       // fallback (deg > EDGE_CAP): recompute
            s = col[start + j];
            #pragma unroll
            for (int hh = 0; hh < H; ++hh) {
                float e = als[s * H + hh] + aldv[hh];
                e = (e >= 0.f) ? e : 0.2f * e;
                w[hh] = expf(e - m[hh]) * rd[hh];
            }
        }
        const float* hp = htab + (size_t)s * (H * 64);
        #pragma unroll
        for (int hh = 0; hh < H; ++hh) acc = fmaf(w[hh], hp[hh * 64 + lane], acc);
    }

    float v = acc + bias[lane];
    if (GELU) v = 0.5f * v * (1.f + erff(v * 0.70710678118654752f));
    xout[(size_t)n * 64 + lane] = v;
}

// =================== host launch ===================

extern "C" void kernel_launch(void* const* d_in, const int* in_sizes, int n_in,
                              void* d_out, int out_size, void* d_ws, size_t ws_size,
                              hipStream_t stream) {
    const float* x0  = (const float*)d_in[0];
    const int*   ei  = (const int*)d_in[1];
    const int* srcv = ei;
    const int* dstv = ei + NEDGE;

    const float* W[3]  = { (const float*)d_in[2], (const float*)d_in[6],  (const float*)d_in[10] };
    const float* As[3] = { (const float*)d_in[3], (const float*)d_in[7],  (const float*)d_in[11] };
    const float* Ad[3] = { (const float*)d_in[4], (const float*)d_in[8],  (const float*)d_in[12] };
    const float* B[3]  = { (const float*)d_in[5], (const float*)d_in[9],  (const float*)d_in[13] };

    // workspace layout
    float* wsf   = (float*)d_ws;
    float* h     = wsf;                                  // N*192 f32
    float* als   = h + (size_t)NODES * 192;              // N*3
    float* ald   = als + (size_t)NODES * 3;              // N*3
    float* x1    = ald + (size_t)NODES * 3;              // N*64
    float* x2    = x1 + (size_t)NODES * 64;              // N*64
    int* cnt     = (int*)(x2 + (size_t)NODES * 64);      // N
    int* row_ptr = cnt + NODES;                          // N+1
    int* cursor  = row_ptr + NODES + 1;                  // N
    int* col     = cursor + NODES;                       // ETOT

    const int TB = 256;
    const int edgeBlocks = (ETOT + TB - 1) / TB;
    const int nodeBlocks = NODES / 4;

    // ---- CSR build (self-loops included as virtual edges) ----
    hipMemsetAsync(cnt, 0, NODES * sizeof(int), stream);
    hipLaunchKernelGGL(hist_kernel, dim3(edgeBlocks), dim3(TB), 0, stream, dstv, cnt);
    hipLaunchKernelGGL(scan_csr, dim3(1), dim3(1024), 0, stream, cnt, row_ptr, cursor);
    hipLaunchKernelGGL(fill_csr, dim3(edgeBlocks), dim3(TB), 0, stream, srcv, dstv, cursor, col);

    // ---- layer 0: cin=128, H=3, mean + gelu ----
    hipLaunchKernelGGL((linear_al<128>), dim3(NODES / 128, 3), dim3(TB), 0, stream,
                       x0, W[0], As[0], Ad[0], h, als, ald, 3);
    hipLaunchKernelGGL((node_agg<3, true>), dim3(nodeBlocks), dim3(TB), 0, stream,
                       row_ptr, col, als, ald, h, B[0], x1);

    // ---- layer 1: cin=64, H=3, mean + gelu ----
    hipLaunchKernelGGL((linear_al<64>), dim3(NODES / 128, 3), dim3(TB), 0, stream,
                       x1, W[1], As[1], Ad[1], h, als, ald, 3);
    hipLaunchKernelGGL((node_agg<3, true>), dim3(nodeBlocks), dim3(TB), 0, stream,
                       row_ptr, col, als, ald, h, B[1], x2);

    // ---- layer 2: cin=64, H=1, concat, no activation ----
    hipLaunchKernelGGL((linear_al<64>), dim3(NODES / 128, 1), dim3(TB), 0, stream,
                       x2, W[2], As[2], Ad[2], h, als, ald, 1);
    hipLaunchKernelGGL((node_agg<1, false>), dim3(nodeBlocks), dim3(TB), 0, stream,
                       row_ptr, col, als, ald, h, B[2], (float*)d_out);
}

// Round 5
// 268.008 us; speedup vs baseline: 3.4209x; 1.0841x over previous
//
#include <hip/hip_runtime.h>
#include <math.h>

#define NODES 32768
#define NEDGE 524288
#define ETOT  (NEDGE + NODES)

// =================== CSR build (once per call) ===================

__global__ void hist_kernel(const int* __restrict__ dstv, int* __restrict__ cnt)
{
    int e = blockIdx.x * blockDim.x + threadIdx.x;
    if (e >= ETOT) return;
    int d = (e < NEDGE) ? dstv[e] : (e - NEDGE);
    atomicAdd(&cnt[d], 1);
}

// single block, 1024 threads, 32 elements each -> exclusive scan of 32768 counts
__global__ __launch_bounds__(1024) void scan_csr(const int* __restrict__ cnt,
                                                 int* __restrict__ row_ptr,
                                                 int* __restrict__ cursor)
{
    __shared__ int ssum[1024];
    const int t = threadIdx.x;
    const int base = t * 32;
    int local[32];
    int s = 0;
    #pragma unroll
    for (int i = 0; i < 32; ++i) { local[i] = cnt[base + i]; s += local[i]; }
    ssum[t] = s;
    __syncthreads();
    for (int off = 1; off < 1024; off <<= 1) {
        int x = ssum[t];
        int y = (t >= off) ? ssum[t - off] : 0;
        __syncthreads();
        ssum[t] = x + y;
        __syncthreads();
    }
    int run = ssum[t] - s;           // exclusive prefix
    #pragma unroll
    for (int i = 0; i < 32; ++i) {
        row_ptr[base + i] = run;
        cursor[base + i] = run;
        run += local[i];
    }
    if (t == 1023) row_ptr[NODES] = run;
}

__global__ void fill_csr(const int* __restrict__ srcv, const int* __restrict__ dstv,
                         int* __restrict__ cursor, int* __restrict__ col)
{
    int e = blockIdx.x * blockDim.x + threadIdx.x;
    if (e >= ETOT) return;
    int s, d;
    if (e < NEDGE) { s = srcv[e]; d = dstv[e]; } else { s = d = e - NEDGE; }
    int pos = atomicAdd(&cursor[d], 1);
    col[pos] = s;
}

// =================== h = x @ W, fused al_s/al_d reductions ===================
// grid: (NODES/128, H). block: 256 threads.
// thread (cg = tid&15, ng = tid>>4) owns 8 nodes x 4 cols of this head's slab.
// als/ald written PADDED at stride 4 (float4-gatherable).
template<int K>
__global__ __launch_bounds__(256) void linear_al(
    const float* __restrict__ x, const float* __restrict__ W,   // W: [K][M] k-major
    const float* __restrict__ a_s, const float* __restrict__ a_d,
    float* __restrict__ h, float* __restrict__ als4, float* __restrict__ ald4,
    int H)
{
    constexpr int KT = 64;
    __shared__ float xs[128 * KT];   // slot: row*16 + (q ^ ((row>>3)&3)), q = k/4
    __shared__ float ws[KT * 64];    // [kk][c]
    const int tid = threadIdx.x;
    const int cg = tid & 15;
    const int ng = tid >> 4;
    const int head = blockIdx.y;
    const int n0 = blockIdx.x * 128;
    const int M = H << 6;

    float acc[8][4];
    #pragma unroll
    for (int r = 0; r < 8; ++r)
        #pragma unroll
        for (int j = 0; j < 4; ++j) acc[r][j] = 0.f;

    for (int k0 = 0; k0 < K; k0 += KT) {
        #pragma unroll
        for (int it = 0; it < 8; ++it) {
            int u = tid + it * 256;
            int row = u >> 4, q = u & 15;
            float4 v = *reinterpret_cast<const float4*>(
                &x[(size_t)(n0 + row) * K + k0 + q * 4]);
            int slot = row * 16 + (q ^ ((row >> 3) & 3));
            *reinterpret_cast<float4*>(&xs[slot * 4]) = v;
        }
        #pragma unroll
        for (int it = 0; it < 4; ++it) {
            int u = tid + it * 256;
            int kk = u >> 4, cq = u & 15;
            float4 v = *reinterpret_cast<const float4*>(
                &W[(size_t)(k0 + kk) * M + head * 64 + cq * 4]);
            *reinterpret_cast<float4*>(&ws[kk * 64 + cq * 4]) = v;
        }
        __syncthreads();

        #pragma unroll
        for (int q = 0; q < 16; ++q) {
            float4 wv[4];
            #pragma unroll
            for (int i = 0; i < 4; ++i)
                wv[i] = *reinterpret_cast<const float4*>(&ws[(q * 4 + i) * 64 + cg * 4]);
            #pragma unroll
            for (int r = 0; r < 8; ++r) {
                const int row = ng * 8 + r;
                const int slot = row * 16 + (q ^ ((row >> 3) & 3));
                float4 xv = *reinterpret_cast<const float4*>(&xs[slot * 4]);
                acc[r][0] = fmaf(xv.x, wv[0].x, fmaf(xv.y, wv[1].x, fmaf(xv.z, wv[2].x, fmaf(xv.w, wv[3].x, acc[r][0]))));
                acc[r][1] = fmaf(xv.x, wv[0].y, fmaf(xv.y, wv[1].y, fmaf(xv.z, wv[2].y, fmaf(xv.w, wv[3].y, acc[r][1]))));
                acc[r][2] = fmaf(xv.x, wv[0].z, fmaf(xv.y, wv[1].z, fmaf(xv.z, wv[2].z, fmaf(xv.w, wv[3].z, acc[r][2]))));
                acc[r][3] = fmaf(xv.x, wv[0].w, fmaf(xv.y, wv[1].w, fmaf(xv.z, wv[2].w, fmaf(xv.w, wv[3].w, acc[r][3]))));
            }
        }
        __syncthreads();
    }

    const int c0 = head * 64 + cg * 4;
    const float* asp = a_s + c0;
    const float* adp = a_d + c0;
    const float s0 = asp[0], s1 = asp[1], s2 = asp[2], s3 = asp[3];
    const float d0 = adp[0], d1 = adp[1], d2 = adp[2], d3 = adp[3];

    #pragma unroll
    for (int r = 0; r < 8; ++r) {
        const int n = n0 + ng * 8 + r;
        float4 hv;
        hv.x = acc[r][0]; hv.y = acc[r][1]; hv.z = acc[r][2]; hv.w = acc[r][3];
        *reinterpret_cast<float4*>(&h[(size_t)n * M + c0]) = hv;
        float ps = acc[r][0] * s0 + acc[r][1] * s1 + acc[r][2] * s2 + acc[r][3] * s3;
        float pd = acc[r][0] * d0 + acc[r][1] * d1 + acc[r][2] * d2 + acc[r][3] * d3;
        #pragma unroll
        for (int off = 1; off < 16; off <<= 1) {
            ps += __shfl_xor(ps, off, 64);
            pd += __shfl_xor(pd, off, 64);
        }
        if (cg == 0) { als4[(size_t)n * 4 + head] = ps; ald4[(size_t)n * 4 + head] = pd; }
    }
}

// =================== fused per-node softmax + aggregate + bias(+gelu) ===================
// one wave per dst node; lane = output channel (phase B) / edge slot (phase A).
// 4 nodes per 256-thread block. deg<=64 fast path fully in-register.
template<int H, bool GELU>
__global__ __launch_bounds__(256) void node_agg(
    const int* __restrict__ row_ptr, const int* __restrict__ col,
    const float* __restrict__ als4, const float* __restrict__ ald4,
    const float* __restrict__ htab, const float* __restrict__ bias,
    float* __restrict__ xout)
{
    __shared__ float swt[4][64 * H];
    __shared__ int   scol[4][64];
    const int wid = threadIdx.x >> 6;
    const int lane = threadIdx.x & 63;
    const int n = blockIdx.x * 4 + wid;
    const int start = row_ptr[n], end = row_ptr[n + 1];
    const int deg = end - start;
    const int dcap = deg < 64 ? deg : 64;

    float aldv[H];
    #pragma unroll
    for (int hh = 0; hh < H; ++hh) aldv[hh] = ald4[(size_t)n * 4 + hh];

    // ---- phase A: one gather per edge slot; softmax in registers ----
    float e[H], m[H];
    #pragma unroll
    for (int hh = 0; hh < H; ++hh) { e[hh] = -INFINITY; m[hh] = -INFINITY; }
    if (lane < dcap) {
        int s = col[start + lane];
        scol[wid][lane] = s;
        float4 av = *reinterpret_cast<const float4*>(&als4[(size_t)s * 4]);
        float avv[4]; avv[0] = av.x; avv[1] = av.y; avv[2] = av.z; avv[3] = av.w;
        #pragma unroll
        for (int hh = 0; hh < H; ++hh) {
            float t = avv[hh] + aldv[hh];
            t = (t >= 0.f) ? t : 0.2f * t;
            e[hh] = t; m[hh] = t;
        }
    }
    // extras (deg > 64, ~never): max pass
    for (int i = start + 64 + lane; i < end; i += 64) {
        int s = col[i];
        float4 av = *reinterpret_cast<const float4*>(&als4[(size_t)s * 4]);
        float avv[4]; avv[0] = av.x; avv[1] = av.y; avv[2] = av.z; avv[3] = av.w;
        #pragma unroll
        for (int hh = 0; hh < H; ++hh) {
            float t = avv[hh] + aldv[hh];
            t = (t >= 0.f) ? t : 0.2f * t;
            m[hh] = fmaxf(m[hh], t);
        }
    }
    #pragma unroll
    for (int hh = 0; hh < H; ++hh)
        #pragma unroll
        for (int off = 1; off < 64; off <<= 1)
            m[hh] = fmaxf(m[hh], __shfl_xor(m[hh], off, 64));

    float myex[H], sum[H];
    #pragma unroll
    for (int hh = 0; hh < H; ++hh) {
        myex[hh] = expf(e[hh] - m[hh]);          // e=-inf for idle lanes -> 0
        sum[hh] = myex[hh];
    }
    // extras: sum pass (recompute)
    for (int i = start + 64 + lane; i < end; i += 64) {
        int s = col[i];
        float4 av = *reinterpret_cast<const float4*>(&als4[(size_t)s * 4]);
        float avv[4]; avv[0] = av.x; avv[1] = av.y; avv[2] = av.z; avv[3] = av.w;
        #pragma unroll
        for (int hh = 0; hh < H; ++hh) {
            float t = avv[hh] + aldv[hh];
            t = (t >= 0.f) ? t : 0.2f * t;
            sum[hh] += expf(t - m[hh]);
        }
    }
    #pragma unroll
    for (int hh = 0; hh < H; ++hh)
        #pragma unroll
        for (int off = 1; off < 64; off <<= 1)
            sum[hh] += __shfl_xor(sum[hh], off, 64);

    const float scale = (H == 1) ? 1.f : (1.f / (float)H);
    float rd[H];
    #pragma unroll
    for (int hh = 0; hh < H; ++hh) rd[hh] = scale / sum[hh];

    if (lane < dcap) {
        #pragma unroll
        for (int hh = 0; hh < H; ++hh) swt[wid][lane * H + hh] = myex[hh] * rd[hh];
    }

    // ---- phase B: 4-way unrolled aggregation, 4 independent accumulators ----
    float av0 = 0.f, av1 = 0.f, av2 = 0.f, av3 = 0.f;
    int j = 0;
    for (; j + 4 <= dcap; j += 4) {
        const float* pp[4];
        float ww[4][H];
        #pragma unroll
        for (int u = 0; u < 4; ++u) {
            int s = scol[wid][j + u];
            pp[u] = htab + (size_t)s * (H * 64);
            #pragma unroll
            for (int hh = 0; hh < H; ++hh) ww[u][hh] = swt[wid][(j + u) * H + hh];
        }
        #pragma unroll
        for (int hh = 0; hh < H; ++hh) {
            av0 = fmaf(ww[0][hh], pp[0][hh * 64 + lane], av0);
            av1 = fmaf(ww[1][hh], pp[1][hh * 64 + lane], av1);
            av2 = fmaf(ww[2][hh], pp[2][hh * 64 + lane], av2);
            av3 = fmaf(ww[3][hh], pp[3][hh * 64 + lane], av3);
        }
    }
    for (; j < dcap; ++j) {
        int s = scol[wid][j];
        const float* hp = htab + (size_t)s * (H * 64);
        #pragma unroll
        for (int hh = 0; hh < H; ++hh)
            av0 = fmaf(swt[wid][j * H + hh], hp[hh * 64 + lane], av0);
    }
    // extras (deg > 64): uniform recompute path
    for (int jj = 64; jj < deg; ++jj) {
        int s = col[start + jj];
        float4 av = *reinterpret_cast<const float4*>(&als4[(size_t)s * 4]);
        float avv[4]; avv[0] = av.x; avv[1] = av.y; avv[2] = av.z; avv[3] = av.w;
        const float* hp = htab + (size_t)s * (H * 64);
        #pragma unroll
        for (int hh = 0; hh < H; ++hh) {
            float t = avv[hh] + aldv[hh];
            t = (t >= 0.f) ? t : 0.2f * t;
            float w = expf(t - m[hh]) * rd[hh];
            av0 = fmaf(w, hp[hh * 64 + lane], av0);
        }
    }

    float v = (av0 + av1) + (av2 + av3) + bias[lane];
    if (GELU) v = 0.5f * v * (1.f + erff(v * 0.70710678118654752f));
    xout[(size_t)n * 64 + lane] = v;
}

// =================== host launch ===================

extern "C" void kernel_launch(void* const* d_in, const int* in_sizes, int n_in,
                              void* d_out, int out_size, void* d_ws, size_t ws_size,
                              hipStream_t stream) {
    const float* x0  = (const float*)d_in[0];
    const int*   ei  = (const int*)d_in[1];
    const int* srcv = ei;
    const int* dstv = ei + NEDGE;

    const float* W[3]  = { (const float*)d_in[2], (const float*)d_in[6],  (const float*)d_in[10] };
    const float* As[3] = { (const float*)d_in[3], (const float*)d_in[7],  (const float*)d_in[11] };
    const float* Ad[3] = { (const float*)d_in[4], (const float*)d_in[8],  (const float*)d_in[12] };
    const float* B[3]  = { (const float*)d_in[5], (const float*)d_in[9],  (const float*)d_in[13] };

    // workspace layout
    float* wsf   = (float*)d_ws;
    float* h     = wsf;                                  // N*192 f32
    float* als4  = h + (size_t)NODES * 192;              // N*4 (padded)
    float* ald4  = als4 + (size_t)NODES * 4;             // N*4 (padded)
    float* x1    = ald4 + (size_t)NODES * 4;             // N*64
    float* x2    = x1 + (size_t)NODES * 64;              // N*64
    int* cnt     = (int*)(x2 + (size_t)NODES * 64);      // N
    int* row_ptr = cnt + NODES;                          // N+1
    int* cursor  = row_ptr + NODES + 1;                  // N
    int* col     = cursor + NODES;                       // ETOT

    const int TB = 256;
    const int edgeBlocks = (ETOT + TB - 1) / TB;
    const int nodeBlocks = NODES / 4;

    // ---- CSR build (self-loops included as virtual edges) ----
    hipMemsetAsync(cnt, 0, NODES * sizeof(int), stream);
    hipLaunchKernelGGL(hist_kernel, dim3(edgeBlocks), dim3(TB), 0, stream, dstv, cnt);
    hipLaunchKernelGGL(scan_csr, dim3(1), dim3(1024), 0, stream, cnt, row_ptr, cursor);
    hipLaunchKernelGGL(fill_csr, dim3(edgeBlocks), dim3(TB), 0, stream, srcv, dstv, cursor, col);

    // ---- layer 0: cin=128, H=3, mean + gelu ----
    hipLaunchKernelGGL((linear_al<128>), dim3(NODES / 128, 3), dim3(TB), 0, stream,
                       x0, W[0], As[0], Ad[0], h, als4, ald4, 3);
    hipLaunchKernelGGL((node_agg<3, true>), dim3(nodeBlocks), dim3(TB), 0, stream,
                       row_ptr, col, als4, ald4, h, B[0], x1);

    // ---- layer 1: cin=64, H=3, mean + gelu ----
    hipLaunchKernelGGL((linear_al<64>), dim3(NODES / 128, 3), dim3(TB), 0, stream,
                       x1, W[1], As[1], Ad[1], h, als4, ald4, 3);
    hipLaunchKernelGGL((node_agg<3, true>), dim3(nodeBlocks), dim3(TB), 0, stream,
                       row_ptr, col, als4, ald4, h, B[1], x2);

    // ---- layer 2: cin=64, H=1, concat, no activation ----
    hipLaunchKernelGGL((linear_al<64>), dim3(NODES / 128, 1), dim3(TB), 0, stream,
                       x2, W[2], As[2], Ad[2], h, als4, ald4, 1);
    hipLaunchKernelGGL((node_agg<1, false>), dim3(nodeBlocks), dim3(TB), 0, stream,
                       row_ptr, col, als4, ald4, h, B[2], (float*)d_out);
}